// Round 1
// baseline (130.296 us; speedup 1.0000x reference)
//
#include <hip/hip_runtime.h>
#include <hip/hip_bf16.h>

typedef __bf16 bf16x8 __attribute__((ext_vector_type(8)));
typedef float f32x4 __attribute__((ext_vector_type(4)));

#define NROWS 8192
#define HALF_N 4096
#define DIM 128
#define TINV 10.0f
#define C1 14.42695040888963f   /* (1/T) * log2(e) */
#define LN2 0.6931471805599453f
#define COL_SPLITS 8

// ---------------- kernel 1: row-normalize into bf16 ----------------
__global__ __launch_bounds__(256) void k_normalize(
    const float* __restrict__ zi, const float* __restrict__ zj,
    __bf16* __restrict__ rn)
{
    const int row  = blockIdx.x * 4 + (threadIdx.x >> 6);
    const int lane = threadIdx.x & 63;
    const float* src = (row < HALF_N) ? (zi + (size_t)row * DIM)
                                      : (zj + (size_t)(row - HALF_N) * DIM);
    float2 v = *(const float2*)(src + lane * 2);
    float ss = v.x * v.x + v.y * v.y;
    #pragma unroll
    for (int m = 32; m >= 1; m >>= 1) ss += __shfl_xor(ss, m, 64);
    const float scale = 1.0f / fmaxf(sqrtf(ss), 1e-8f);
    __bf16* dst = rn + (size_t)row * DIM + lane * 2;
    dst[0] = (__bf16)(v.x * scale);
    dst[1] = (__bf16)(v.y * scale);
}

// ---------------- kernel 2: sim GEMM + exp rowsum ----------------
// Tile: 128 rows x 128 cols per block, K=128 (full). 4 waves; wave (w1,w0)
// owns a 64x64 quadrant as 4x4 MFMA 16x16x32 subtiles. A-frags in regs.
__global__ __launch_bounds__(256) void k_simsum(
    const __bf16* __restrict__ rn, float* __restrict__ rowsum)
{
    __shared__ __bf16 lds[128 * DIM];   // 32 KB, reused for A then B tiles
    const int tid  = threadIdx.x;
    const int wave = tid >> 6;
    const int lane = tid & 63;
    const int tile_m = blockIdx.x * 128;
    const int w0 = wave & 1, w1 = wave >> 1;
    const int qrow = lane >> 4;
    const int lcol = lane & 15;

    // ---- stage A: rows [tile_m, tile_m+128) x K=128, contiguous 32 KB ----
    {
        const char* gA = (const char*)(rn + (size_t)tile_m * DIM);
        #pragma unroll
        for (int i = 0; i < 8; ++i) {
            const int off = wave * 8192 + i * 1024;
            __builtin_amdgcn_global_load_lds(
                (const __attribute__((address_space(1))) void*)(gA + off + lane * 16),
                (__attribute__((address_space(3))) void*)((char*)lds + off),
                16, 0, 0);
        }
    }
    __syncthreads();

    // A fragments: A[m = lane&15][k = quad*8 + j], 4 m-subtiles x 4 k-steps
    bf16x8 afrag[4][4];
    #pragma unroll
    for (int mi = 0; mi < 4; ++mi) {
        const int m = w1 * 64 + mi * 16 + lcol;
        #pragma unroll
        for (int ks = 0; ks < 4; ++ks)
            afrag[mi][ks] = *(const bf16x8*)(lds + m * DIM + ks * 32 + qrow * 8);
    }
    __syncthreads();   // all waves done reading A; LDS free for B tiles

    float rsum[4][4];  // [mi][reg] partial exp-sums; row = w1*64+mi*16+qrow*4+r
    #pragma unroll
    for (int mi = 0; mi < 4; ++mi)
        #pragma unroll
        for (int r = 0; r < 4; ++r) rsum[mi][r] = 0.0f;

    const int col_base = blockIdx.y * (NROWS / COL_SPLITS);
    const int iters = (NROWS / COL_SPLITS) / 128;   // 8
    for (int it = 0; it < iters; ++it) {
        const char* gB = (const char*)(rn + (size_t)(col_base + it * 128) * DIM);
        #pragma unroll
        for (int i = 0; i < 8; ++i) {
            const int off = wave * 8192 + i * 1024;
            __builtin_amdgcn_global_load_lds(
                (const __attribute__((address_space(1))) void*)(gB + off + lane * 16),
                (__attribute__((address_space(3))) void*)((char*)lds + off),
                16, 0, 0);
        }
        __syncthreads();

        f32x4 acc[4][4];
        const f32x4 zero = {0.0f, 0.0f, 0.0f, 0.0f};
        #pragma unroll
        for (int mi = 0; mi < 4; ++mi)
            #pragma unroll
            for (int ni = 0; ni < 4; ++ni) acc[mi][ni] = zero;

        #pragma unroll
        for (int ks = 0; ks < 4; ++ks) {
            bf16x8 bfrag[4];
            #pragma unroll
            for (int ni = 0; ni < 4; ++ni) {
                const int n = w0 * 64 + ni * 16 + lcol;
                bfrag[ni] = *(const bf16x8*)(lds + n * DIM + ks * 32 + qrow * 8);
            }
            #pragma unroll
            for (int mi = 0; mi < 4; ++mi)
                #pragma unroll
                for (int ni = 0; ni < 4; ++ni)
                    acc[mi][ni] = __builtin_amdgcn_mfma_f32_16x16x32_bf16(
                        afrag[mi][ks], bfrag[ni], acc[mi][ni], 0, 0, 0);
        }
        __syncthreads();   // ds_reads done; LDS free for next B stage

        // epilogue: rowsum += exp((s-1)/T), computed as exp2(s*C1 - C1)
        #pragma unroll
        for (int mi = 0; mi < 4; ++mi)
            #pragma unroll
            for (int ni = 0; ni < 4; ++ni)
                #pragma unroll
                for (int r = 0; r < 4; ++r)
                    rsum[mi][r] += __builtin_amdgcn_exp2f(acc[mi][ni][r] * C1 - C1);
    }

    // reduce across the 16 col-lanes of each quad, then one atomic per row
    #pragma unroll
    for (int mi = 0; mi < 4; ++mi)
        #pragma unroll
        for (int r = 0; r < 4; ++r) {
            float v = rsum[mi][r];
            v += __shfl_xor(v, 1, 64);
            v += __shfl_xor(v, 2, 64);
            v += __shfl_xor(v, 4, 64);
            v += __shfl_xor(v, 8, 64);
            if (lcol == 0)
                atomicAdd(&rowsum[tile_m + w1 * 64 + mi * 16 + qrow * 4 + r], v);
        }
}

// ---------------- kernel 3: finalize ----------------
// loss_k = 1/T + ln(rowsum_k + exp((p_k-1)/T)) - p_k/T ; out = sum/8192
__global__ __launch_bounds__(256) void k_finalize(
    const __bf16* __restrict__ rn, const float* __restrict__ rowsum,
    float* __restrict__ out)
{
    const int row  = blockIdx.x * 4 + (threadIdx.x >> 6);
    const int wave = threadIdx.x >> 6;
    const int lane = threadIdx.x & 63;
    const int partner = (row + HALF_N) & (NROWS - 1);
    const __bf16* a = rn + (size_t)row * DIM + lane * 2;
    const __bf16* b = rn + (size_t)partner * DIM + lane * 2;
    float p = (float)a[0] * (float)b[0] + (float)a[1] * (float)b[1];
    #pragma unroll
    for (int m = 32; m >= 1; m >>= 1) p += __shfl_xor(p, m, 64);

    __shared__ float part[4];
    if (lane == 0) {
        float s = rowsum[row] + __builtin_amdgcn_exp2f(p * C1 - C1);
        part[wave] = TINV + __builtin_amdgcn_logf(s) * LN2 - TINV * p;
    }
    __syncthreads();
    if (threadIdx.x == 0)
        atomicAdd(out, (part[0] + part[1] + part[2] + part[3]) * (1.0f / (float)NROWS));
}

extern "C" void kernel_launch(void* const* d_in, const int* in_sizes, int n_in,
                              void* d_out, int out_size, void* d_ws, size_t ws_size,
                              hipStream_t stream)
{
    const float* zi = (const float*)d_in[0];
    const float* zj = (const float*)d_in[1];
    float* out = (float*)d_out;

    // ws layout: [0, 2MB) rn bf16 (8192x128); [2MB, +32KB) rowsum f32[8192]
    __bf16* rn     = (__bf16*)d_ws;
    float*  rowsum = (float*)((char*)d_ws + (size_t)NROWS * DIM * sizeof(__bf16));

    // harness poisons d_out/d_ws with 0xAA before every timed launch
    hipMemsetAsync(out, 0, sizeof(float), stream);
    hipMemsetAsync(rowsum, 0, NROWS * sizeof(float), stream);

    k_normalize<<<NROWS / 4, 256, 0, stream>>>(zi, zj, rn);
    k_simsum<<<dim3(NROWS / 128, COL_SPLITS), 256, 0, stream>>>(rn, rowsum);
    k_finalize<<<NROWS / 4, 256, 0, stream>>>(rn, rowsum, out);
}

// Round 2
// 105.035 us; speedup vs baseline: 1.2405x; 1.2405x over previous
//
#include <hip/hip_runtime.h>
#include <hip/hip_bf16.h>

typedef __bf16 bf16x8 __attribute__((ext_vector_type(8)));
typedef __bf16 bf16x2 __attribute__((ext_vector_type(2)));
typedef float f32x4 __attribute__((ext_vector_type(4)));

#define NROWS 8192
#define HALF_N 4096
#define DIM 128
#define ROW_BYTES 256          /* 128 bf16 */
#define TINV 10.0f
#define C1 14.42695040888963f  /* (1/T) * log2(e) */
#define LN2 0.6931471805599453f
#define COL_SPLITS 16

/* rn is stored GLOBALLY swizzled: 16B chunk kc of row r lives at
   r*256 + (kc ^ (r&7))*16.  global_load_lds copies verbatim, so LDS tiles
   inherit the swizzle and MFMA fragment reads spread uniformly over all
   32 banks (8 dwords/bank = floor) instead of 16-way conflicting. */
#define SWZ(r, kc) ((kc) ^ ((r) & 7))

// ---------------- kernel 1: row-normalize into swizzled bf16; also zero rowsum
__global__ __launch_bounds__(256) void k_normalize(
    const float* __restrict__ zi, const float* __restrict__ zj,
    char* __restrict__ rn, float* __restrict__ rowsum)
{
    const int row  = blockIdx.x * 4 + (threadIdx.x >> 6);
    const int lane = threadIdx.x & 63;
    const float* src = (row < HALF_N) ? (zi + (size_t)row * DIM)
                                      : (zj + (size_t)(row - HALF_N) * DIM);
    float2 v = *(const float2*)(src + lane * 2);
    float ss = v.x * v.x + v.y * v.y;
    #pragma unroll
    for (int m = 32; m >= 1; m >>= 1) ss += __shfl_xor(ss, m, 64);
    const float scale = 1.0f / fmaxf(sqrtf(ss), 1e-8f);
    bf16x2 o; o[0] = (__bf16)(v.x * scale); o[1] = (__bf16)(v.y * scale);
    // logical byte offset lane*4 -> chunk kc = lane>>2, rem (lane&3)*4
    char* dst = rn + (size_t)row * ROW_BYTES + SWZ(row, lane >> 2) * 16 + (lane & 3) * 4;
    *(bf16x2*)dst = o;
    // fold rowsum zeroing into this kernel (runs before k_simsum's atomics)
    if (blockIdx.x < 32) rowsum[blockIdx.x * 256 + threadIdx.x] = 0.0f;
}

// ---------------- kernel 2: sim GEMM + exp rowsum ----------------
// 128x128 tile per block, K=128 one-shot. 4 waves in 2x2 quadrants,
// each wave 4x4 MFMA 16x16x32 subtiles, A-frags cached in registers.
__global__ __launch_bounds__(256) void k_simsum(
    const char* __restrict__ rn, float* __restrict__ rowsum)
{
    __shared__ char lds[128 * ROW_BYTES];   // 32 KB, reused A then B
    const int tid  = threadIdx.x;
    const int wave = tid >> 6;
    const int lane = tid & 63;
    const int tile_m = blockIdx.x * 128;
    const int w0 = wave & 1, w1 = wave >> 1;
    const int qrow = lane >> 4;
    const int lcol = lane & 15;

    // ---- stage A rows [tile_m, +128): contiguous 32 KB DMA ----
    {
        const char* gA = rn + (size_t)tile_m * ROW_BYTES;
        #pragma unroll
        for (int i = 0; i < 8; ++i) {
            const int off = wave * 8192 + i * 1024;
            __builtin_amdgcn_global_load_lds(
                (const __attribute__((address_space(1))) void*)(gA + off + lane * 16),
                (__attribute__((address_space(3))) void*)(lds + off),
                16, 0, 0);
        }
    }
    __syncthreads();

    // A fragments: A[m = lane&15][k = qrow*8 + j]; swizzled chunk address
    bf16x8 afrag[4][4];
    #pragma unroll
    for (int mi = 0; mi < 4; ++mi) {
        const int m = w1 * 64 + mi * 16 + lcol;
        #pragma unroll
        for (int ks = 0; ks < 4; ++ks)
            afrag[mi][ks] = *(const bf16x8*)(lds + m * ROW_BYTES + SWZ(m, ks * 4 + qrow) * 16);
    }
    __syncthreads();   // LDS free for B tiles

    float rsum[4][4];
    #pragma unroll
    for (int mi = 0; mi < 4; ++mi)
        #pragma unroll
        for (int r = 0; r < 4; ++r) rsum[mi][r] = 0.0f;

    const int col_base = blockIdx.y * (NROWS / COL_SPLITS);
    const int iters = (NROWS / COL_SPLITS) / 128;   // 4
    for (int it = 0; it < iters; ++it) {
        const char* gB = rn + (size_t)(col_base + it * 128) * ROW_BYTES;
        #pragma unroll
        for (int i = 0; i < 8; ++i) {
            const int off = wave * 8192 + i * 1024;
            __builtin_amdgcn_global_load_lds(
                (const __attribute__((address_space(1))) void*)(gB + off + lane * 16),
                (__attribute__((address_space(3))) void*)(lds + off),
                16, 0, 0);
        }
        __syncthreads();

        f32x4 acc[4][4];
        const f32x4 zero = {0.0f, 0.0f, 0.0f, 0.0f};
        #pragma unroll
        for (int mi = 0; mi < 4; ++mi)
            #pragma unroll
            for (int ni = 0; ni < 4; ++ni) acc[mi][ni] = zero;

        #pragma unroll
        for (int ks = 0; ks < 4; ++ks) {
            bf16x8 bfrag[4];
            #pragma unroll
            for (int ni = 0; ni < 4; ++ni) {
                const int n = w0 * 64 + ni * 16 + lcol;
                bfrag[ni] = *(const bf16x8*)(lds + n * ROW_BYTES + SWZ(n, ks * 4 + qrow) * 16);
            }
            #pragma unroll
            for (int mi = 0; mi < 4; ++mi)
                #pragma unroll
                for (int ni = 0; ni < 4; ++ni)
                    acc[mi][ni] = __builtin_amdgcn_mfma_f32_16x16x32_bf16(
                        afrag[mi][ks], bfrag[ni], acc[mi][ni], 0, 0, 0);
        }
        __syncthreads();

        // rowsum += exp((s-1)/T) = exp2(s*C1 - C1)
        #pragma unroll
        for (int mi = 0; mi < 4; ++mi)
            #pragma unroll
            for (int ni = 0; ni < 4; ++ni)
                #pragma unroll
                for (int r = 0; r < 4; ++r)
                    rsum[mi][r] += __builtin_amdgcn_exp2f(acc[mi][ni][r] * C1 - C1);
    }

    #pragma unroll
    for (int mi = 0; mi < 4; ++mi)
        #pragma unroll
        for (int r = 0; r < 4; ++r) {
            float v = rsum[mi][r];
            v += __shfl_xor(v, 1, 64);
            v += __shfl_xor(v, 2, 64);
            v += __shfl_xor(v, 4, 64);
            v += __shfl_xor(v, 8, 64);
            if (lcol == 0)
                atomicAdd(&rowsum[tile_m + w1 * 64 + mi * 16 + qrow * 4 + r], v);
        }
}

// ---------------- kernel 3: per-row loss (NO atomics) ----------------
// loss_k = 1/T + ln(rowsum_k + exp((p_k-1)/T)) - p_k/T
__global__ __launch_bounds__(256) void k_finalize(
    const char* __restrict__ rn, const float* __restrict__ rowsum,
    float* __restrict__ row_loss)
{
    const int row  = blockIdx.x * 4 + (threadIdx.x >> 6);
    const int lane = threadIdx.x & 63;
    const int partner = (row + HALF_N) & (NROWS - 1);
    const __bf16* a = (const __bf16*)(rn + (size_t)row * ROW_BYTES
                         + SWZ(row, lane >> 2) * 16 + (lane & 3) * 4);
    const __bf16* b = (const __bf16*)(rn + (size_t)partner * ROW_BYTES
                         + SWZ(partner, lane >> 2) * 16 + (lane & 3) * 4);
    float p = (float)a[0] * (float)b[0] + (float)a[1] * (float)b[1];
    #pragma unroll
    for (int m = 32; m >= 1; m >>= 1) p += __shfl_xor(p, m, 64);
    if (lane == 0) {
        float s = rowsum[row] + __builtin_amdgcn_exp2f(p * C1 - C1);
        row_loss[row] = TINV + __builtin_amdgcn_logf(s) * LN2 - TINV * p;
    }
}

// ---------------- kernel 4: single-block reduce -> out ----------------
__global__ __launch_bounds__(256) void k_reduce(
    const float* __restrict__ row_loss, float* __restrict__ out)
{
    const f32x4* v4 = (const f32x4*)row_loss;
    float s = 0.0f;
    for (int i = threadIdx.x; i < NROWS / 4; i += 256) {
        f32x4 v = v4[i];
        s += (v[0] + v[1]) + (v[2] + v[3]);
    }
    #pragma unroll
    for (int m = 32; m >= 1; m >>= 1) s += __shfl_xor(s, m, 64);
    __shared__ float part[4];
    if ((threadIdx.x & 63) == 0) part[threadIdx.x >> 6] = s;
    __syncthreads();
    if (threadIdx.x == 0)
        out[0] = (part[0] + part[1] + part[2] + part[3]) * (1.0f / (float)NROWS);
}

extern "C" void kernel_launch(void* const* d_in, const int* in_sizes, int n_in,
                              void* d_out, int out_size, void* d_ws, size_t ws_size,
                              hipStream_t stream)
{
    const float* zi = (const float*)d_in[0];
    const float* zj = (const float*)d_in[1];
    float* out = (float*)d_out;

    // ws: [0, 2MB) rn (swizzled bf16); [2MB, +32KB) rowsum; [+32KB, +32KB) row_loss
    char*  rn       = (char*)d_ws;
    float* rowsum   = (float*)((char*)d_ws + (size_t)NROWS * ROW_BYTES);
    float* row_loss = rowsum + NROWS;

    k_normalize<<<NROWS / 4, 256, 0, stream>>>(zi, zj, rn, rowsum);
    k_simsum<<<dim3(NROWS / 128, COL_SPLITS), 256, 0, stream>>>(rn, rowsum);
    k_finalize<<<NROWS / 4, 256, 0, stream>>>(rn, rowsum, row_loss);
    k_reduce<<<1, 256, 0, stream>>>(row_loss, out);
}